// Round 1
// baseline (1821.196 us; speedup 1.0000x reference)
//
#include <hip/hip_runtime.h>
#include <hip/hip_bf16.h>

#define DDIM 64
#define NU 150000
#define NI 50000
#define NTOT 200000
#define KU 524
#define KI 1292
#define BM 16
#define BK 128

// ---------------------------------------------------------------------------
// Fused node-feature build + projection.
// Per block: BM=16 rows. Loop K in tiles of BK=128:
//   phase A: build the concatenated input vector tile [16][128] in LDS
//            (id_emb | feat-bag mean | word-text mean | word_embedding | sentence)
//   phase B: accumulate GEMM vs projW column `col` (thread = 1 col x 4 rows)
// Epilogue adds proj bias + numeric@numW + num bias.
// ---------------------------------------------------------------------------
__global__ __launch_bounds__(256) void node_init_kernel(
    const float* __restrict__ id_emb, const float* __restrict__ feat_table,
    const float* __restrict__ word_emb, const float* __restrict__ numeric,
    const float* __restrict__ wordvec, const float* __restrict__ sentence,
    const int* __restrict__ feat_idx, const int* __restrict__ text_idx,
    const float* __restrict__ projW, const float* __restrict__ projb,
    const float* __restrict__ numW, const float* __restrict__ numb,
    float* __restrict__ x_out, int Ktot, int row_off)
{
    __shared__ __align__(16) float a[BM][BK];
    const int row0 = blockIdx.x * BM;
    const int t = threadIdx.x;
    const int col = t & 63;
    const int g = t >> 6;           // wave id 0..3, owns rows g*4 .. g*4+3
    float acc[4] = {0.f, 0.f, 0.f, 0.f};

    for (int k0 = 0; k0 < Ktot; k0 += BK) {
        // ---- phase A: build tile ----
        for (int e = t; e < BM * BK; e += 256) {
            const int r  = e >> 7;       // e / 128
            const int kk = e & 127;
            const int k  = k0 + kk;
            const int row = row0 + r;
            float v = 0.f;
            if (k < 64) {
                v = id_emb[row * 64 + k];
            } else if (k < 128) {
                const int c = k - 64;
                float s = 0.f;
                #pragma unroll
                for (int j = 0; j < 5; ++j)
                    s += feat_table[feat_idx[row * 5 + j] * 64 + c];
                v = s * 0.2f;
            } else if (k < 224) {
                const int kk2 = k - 128;
                const int f = kk2 >> 5, c = kk2 & 31;
                const int* ti = text_idx + (row * 3 + f) * 8;
                float s = 0.f;
                #pragma unroll
                for (int w = 0; w < 8; ++w)
                    s += word_emb[ti[w] * 32 + c];
                v = s * 0.125f;
            } else if (k < 524) {
                v = wordvec[row * 300 + (k - 224)];
            } else if (k < Ktot) {
                v = sentence[row * 768 + (k - 524)];
            }
            a[r][kk] = v;
        }
        __syncthreads();

        // ---- phase B: partial GEMM ----
        const int kmax = min(BK, Ktot - k0);     // always a multiple of 4 here
        for (int kk = 0; kk < kmax; kk += 4) {
            const int kb = k0 + kk;
            const float w0 = projW[(kb + 0) * 64 + col];
            const float w1 = projW[(kb + 1) * 64 + col];
            const float w2 = projW[(kb + 2) * 64 + col];
            const float w3 = projW[(kb + 3) * 64 + col];
            #pragma unroll
            for (int i = 0; i < 4; ++i) {
                const float4 av = *(const float4*)(&a[g * 4 + i][kk]);
                acc[i] += av.x * w0 + av.y * w1 + av.z * w2 + av.w * w3;
            }
        }
        __syncthreads();
    }

    // ---- epilogue: biases + numeric side-GEMM ----
    const float pb = projb[col] + numb[col];
    float wn[10];
    #pragma unroll
    for (int j = 0; j < 10; ++j) wn[j] = numW[j * 64 + col];
    #pragma unroll
    for (int i = 0; i < 4; ++i) {
        const int row = row0 + g * 4 + i;
        float s = acc[i] + pb;
        #pragma unroll
        for (int j = 0; j < 10; ++j) s += numeric[row * 10 + j] * wn[j];
        x_out[(size_t)(row_off + row) * 64 + col] = s;
    }
}

// ---------------------------------------------------------------------------
// One GNN layer: nbr_mean = mean_K x[nbr]; agg = nbr_mean@vW + vb;
// x_next = [x | agg] @ wW + wb  (optional relu)
// ---------------------------------------------------------------------------
__global__ __launch_bounds__(256) void gnn_layer_kernel(
    const float* __restrict__ x, const int* __restrict__ neighbors,
    const float* __restrict__ vW, const float* __restrict__ vb,
    const float* __restrict__ wW, const float* __restrict__ wb,
    float* __restrict__ x_next, int relu_flag)
{
    __shared__ __align__(16) float xs[BM][64];
    __shared__ __align__(16) float nm[BM][64];
    __shared__ __align__(16) float ag[BM][64];
    const int row0 = blockIdx.x * BM;
    const int t = threadIdx.x;
    const int col = t & 63;
    const int g = t >> 6;

    // stage self rows + neighbor means
    #pragma unroll
    for (int i = 0; i < 4; ++i) {
        const int r = g * 4 + i;
        const int row = row0 + r;
        xs[r][col] = x[(size_t)row * 64 + col];
        float s = 0.f;
        #pragma unroll
        for (int j = 0; j < 8; ++j) {
            const int nb = neighbors[row * 8 + j];
            s += x[(size_t)nb * 64 + col];
        }
        nm[r][col] = s * 0.125f;
    }
    __syncthreads();

    // agg = nm @ vW + vb
    #pragma unroll
    for (int i = 0; i < 4; ++i) {
        const int r = g * 4 + i;
        float acc = vb[col];
        for (int k = 0; k < 64; k += 4) {
            const float w0 = vW[(k + 0) * 64 + col];
            const float w1 = vW[(k + 1) * 64 + col];
            const float w2 = vW[(k + 2) * 64 + col];
            const float w3 = vW[(k + 3) * 64 + col];
            const float4 av = *(const float4*)(&nm[r][k]);
            acc += av.x * w0 + av.y * w1 + av.z * w2 + av.w * w3;
        }
        ag[r][col] = acc;
    }
    __syncthreads();

    // x_next = [xs | ag] @ wW + wb
    #pragma unroll
    for (int i = 0; i < 4; ++i) {
        const int r = g * 4 + i;
        float acc = wb[col];
        for (int k = 0; k < 64; k += 4) {
            const float w0 = wW[(k + 0) * 64 + col];
            const float w1 = wW[(k + 1) * 64 + col];
            const float w2 = wW[(k + 2) * 64 + col];
            const float w3 = wW[(k + 3) * 64 + col];
            const float4 av = *(const float4*)(&xs[r][k]);
            acc += av.x * w0 + av.y * w1 + av.z * w2 + av.w * w3;
        }
        for (int k = 0; k < 64; k += 4) {
            const float w0 = wW[(64 + k + 0) * 64 + col];
            const float w1 = wW[(64 + k + 1) * 64 + col];
            const float w2 = wW[(64 + k + 2) * 64 + col];
            const float w3 = wW[(64 + k + 3) * 64 + col];
            const float4 av = *(const float4*)(&ag[r][k]);
            acc += av.x * w0 + av.y * w1 + av.z * w2 + av.w * w3;
        }
        if (relu_flag) acc = fmaxf(acc, 0.f);
        x_next[(size_t)(row0 + r) * 64 + col] = acc;
    }
}

// ---------------------------------------------------------------------------
// Row-wise L2 normalize (clip norm at 1e-12). 4 rows per 256-thread block.
// ---------------------------------------------------------------------------
__global__ __launch_bounds__(256) void normalize_kernel(
    const float* __restrict__ x, float* __restrict__ out)
{
    const int t = threadIdx.x;
    const int col = t & 63;
    const int r = blockIdx.x * 4 + (t >> 6);
    const float v = x[(size_t)r * 64 + col];
    float ss = v * v;
    #pragma unroll
    for (int off = 32; off > 0; off >>= 1) ss += __shfl_xor(ss, off, 64);
    const float nrm = sqrtf(ss);
    out[(size_t)r * 64 + col] = v / fmaxf(nrm, 1e-12f);
}

extern "C" void kernel_launch(void* const* d_in, const int* in_sizes, int n_in,
                              void* d_out, int out_size, void* d_ws, size_t ws_size,
                              hipStream_t stream) {
    const float* user_id_emb        = (const float*)d_in[0];
    const float* item_id_emb        = (const float*)d_in[1];
    const float* user_feat_table    = (const float*)d_in[2];
    const float* item_feat_table    = (const float*)d_in[3];
    const float* word_emb           = (const float*)d_in[4];
    const float* user_numeric       = (const float*)d_in[5];
    const float* item_numeric       = (const float*)d_in[6];
    const float* user_word_embedding= (const float*)d_in[7];
    const float* item_word_embedding= (const float*)d_in[8];
    const float* item_sentence_emb  = (const float*)d_in[9];
    const float* user_num_W         = (const float*)d_in[10];
    const float* user_num_b         = (const float*)d_in[11];
    const float* item_num_W         = (const float*)d_in[12];
    const float* item_num_b         = (const float*)d_in[13];
    const float* user_proj_W        = (const float*)d_in[14];
    const float* user_proj_b        = (const float*)d_in[15];
    const float* item_proj_W        = (const float*)d_in[16];
    const float* item_proj_b        = (const float*)d_in[17];
    const float* w_W                = (const float*)d_in[18];
    const float* w_b                = (const float*)d_in[19];
    const float* v_W                = (const float*)d_in[20];
    const float* v_b                = (const float*)d_in[21];
    const int*   user_feat_idx      = (const int*)d_in[22];
    const int*   item_feat_idx      = (const int*)d_in[23];
    const int*   user_text_idx      = (const int*)d_in[24];
    const int*   item_text_idx      = (const int*)d_in[25];
    const int*   neighbors          = (const int*)d_in[26];

    float* x0 = (float*)d_ws;          // NTOT*64 floats = 51.2 MB
    float* x1 = (float*)d_out;         // reuse output buffer as ping buffer

    // initial node features -> x0
    node_init_kernel<<<NU / BM, 256, 0, stream>>>(
        user_id_emb, user_feat_table, word_emb, user_numeric,
        user_word_embedding, nullptr, user_feat_idx, user_text_idx,
        user_proj_W, user_proj_b, user_num_W, user_num_b, x0, KU, 0);
    node_init_kernel<<<NI / BM, 256, 0, stream>>>(
        item_id_emb, item_feat_table, word_emb, item_numeric,
        item_word_embedding, item_sentence_emb, item_feat_idx, item_text_idx,
        item_proj_W, item_proj_b, item_num_W, item_num_b, x0, KI, NU);

    // layer 0: x0 -> x1 (relu)
    gnn_layer_kernel<<<NTOT / BM, 256, 0, stream>>>(
        x0, neighbors, v_W, v_b, w_W, w_b, x1, 1);
    // layer 1: x1 -> x0 (no relu)
    gnn_layer_kernel<<<NTOT / BM, 256, 0, stream>>>(
        x1, neighbors, v_W + 64 * 64, v_b + 64, w_W + 128 * 64, w_b + 64, x0, 0);

    // normalize x0 -> d_out
    normalize_kernel<<<NTOT / 4, 256, 0, stream>>>(x0, (float*)d_out);
}

// Round 2
// 1748.125 us; speedup vs baseline: 1.0418x; 1.0418x over previous
//
#include <hip/hip_runtime.h>

#define NU 150000
#define NI 50000
#define NTOT 200000
#define KU 524
#define KI 1292
#define SZ (NTOT * 64)

// ---------------------------------------------------------------------------
// Fused node-feature build + projection. 64 rows/block.
// k-tiles of 64: build aT[64 k][64 rows] (transposed, pad 68) in LDS, then
// 4row x 4col register-tiled GEMM vs projW (global b128, L1-hot).
// Indices/numeric staged in LDS once per block.
// ---------------------------------------------------------------------------
__global__ __launch_bounds__(256, 4) void node_init_kernel(
    const float* __restrict__ id_emb, const float* __restrict__ feat_table,
    const float* __restrict__ word_emb, const float* __restrict__ numeric,
    const float* __restrict__ wordvec, const float* __restrict__ sentence,
    const int* __restrict__ feat_idx, const int* __restrict__ text_idx,
    const float* __restrict__ projW, const float* __restrict__ projb,
    const float* __restrict__ numW, const float* __restrict__ numb,
    float* __restrict__ x_out, int n, int Ktot, int row_off)
{
    __shared__ __align__(16) float aT[64][68];   // [k][row], pad 68
    __shared__ int   fi[64][5];
    __shared__ int   ti[64][24];
    __shared__ float nmr[64][10];
    const int t = threadIdx.x;
    const int row0 = blockIdx.x * 64;

    for (int e = t; e < 64 * 5; e += 256) {
        const int r = e / 5, j = e - r * 5, row = row0 + r;
        fi[r][j] = (row < n) ? feat_idx[row * 5 + j] : 0;
    }
    for (int e = t; e < 64 * 24; e += 256) {
        const int r = e / 24, j = e - r * 24, row = row0 + r;
        ti[r][j] = (row < n) ? text_idx[row * 24 + j] : 0;
    }
    for (int e = t; e < 64 * 10; e += 256) {
        const int r = e / 10, j = e - r * 10, row = row0 + r;
        nmr[r][j] = (row < n) ? numeric[(size_t)row * 10 + j] : 0.f;
    }
    __syncthreads();

    const int cg = t & 15, rg = t >> 4;
    const int c0 = cg * 4, r0 = rg * 4;
    const int kk = t & 63, wg = t >> 6;
    float acc[4][4] = {{0.f}};

    for (int k0 = 0; k0 < Ktot; k0 += 64) {
        const int k = k0 + kk;
        // ---- build transposed tile (lane == k for coalesced gathers) ----
        for (int i = 0; i < 16; ++i) {
            const int r = i * 4 + wg;
            const int row = row0 + r;
            float v = 0.f;
            if (row < n && k < Ktot) {
                if (k < 64) {
                    v = id_emb[(size_t)row * 64 + k];
                } else if (k < 128) {
                    float s = 0.f;
                    #pragma unroll
                    for (int j = 0; j < 5; ++j)
                        s += feat_table[(size_t)fi[r][j] * 64 + (k - 64)];
                    v = s * 0.2f;
                } else if (k < 224) {
                    const int k2 = k - 128;
                    const int f = k2 >> 5, c = k2 & 31;
                    float s = 0.f;
                    #pragma unroll
                    for (int w = 0; w < 8; ++w)
                        s += word_emb[(size_t)ti[r][f * 8 + w] * 32 + c];
                    v = s * 0.125f;
                } else if (k < 524) {
                    v = wordvec[(size_t)row * 300 + (k - 224)];
                } else {
                    v = sentence[(size_t)row * 768 + (k - 524)];
                }
            }
            aT[kk][r] = v;
        }
        __syncthreads();

        // ---- register-tiled GEMM ----
        const int klim = min(64, Ktot - k0);
        #pragma unroll 4
        for (int q = 0; q < klim; ++q) {
            const float4 wv = *(const float4*)&projW[(size_t)(k0 + q) * 64 + c0];
            const float4 av = *(const float4*)&aT[q][r0];
            acc[0][0] += av.x * wv.x; acc[0][1] += av.x * wv.y; acc[0][2] += av.x * wv.z; acc[0][3] += av.x * wv.w;
            acc[1][0] += av.y * wv.x; acc[1][1] += av.y * wv.y; acc[1][2] += av.y * wv.z; acc[1][3] += av.y * wv.w;
            acc[2][0] += av.z * wv.x; acc[2][1] += av.z * wv.y; acc[2][2] += av.z * wv.z; acc[2][3] += av.z * wv.w;
            acc[3][0] += av.w * wv.x; acc[3][1] += av.w * wv.y; acc[3][2] += av.w * wv.z; acc[3][3] += av.w * wv.w;
        }
        __syncthreads();
    }

    // ---- epilogue: numeric side-GEMM + biases ----
    #pragma unroll
    for (int m = 0; m < 10; ++m) {
        const float4 wn = *(const float4*)&numW[m * 64 + c0];
        #pragma unroll
        for (int i = 0; i < 4; ++i) {
            const float nv = nmr[r0 + i][m];
            acc[i][0] += nv * wn.x; acc[i][1] += nv * wn.y;
            acc[i][2] += nv * wn.z; acc[i][3] += nv * wn.w;
        }
    }
    const float4 pbv = *(const float4*)&projb[c0];
    const float4 nbv = *(const float4*)&numb[c0];
    #pragma unroll
    for (int i = 0; i < 4; ++i) {
        const int row = row0 + r0 + i;
        if (row < n) {
            float4 o;
            o.x = acc[i][0] + pbv.x + nbv.x;
            o.y = acc[i][1] + pbv.y + nbv.y;
            o.z = acc[i][2] + pbv.z + nbv.z;
            o.w = acc[i][3] + pbv.w + nbv.w;
            *(float4*)&x_out[(size_t)(row_off + row) * 64 + c0] = o;
        }
    }
}

// ---------------------------------------------------------------------------
// GNN layer. 64 rows/block. Transposed LDS tiles, 4x4 register GEMM.
// finalize=0: relu + write.  finalize=1: fused row L2-normalize + write.
// ---------------------------------------------------------------------------
__global__ __launch_bounds__(256, 4) void gnn_layer_kernel(
    const float* __restrict__ x, const int* __restrict__ nbr,
    const float* __restrict__ vW, const float* __restrict__ vb,
    const float* __restrict__ wW, const float* __restrict__ wb,
    float* __restrict__ out, int finalize)
{
    __shared__ __align__(16) float xT[64][68];   // [k][row]
    __shared__ __align__(16) float mT[64][68];   // nbr-mean, then agg
    __shared__ int nbs[64][8];
    const int t = threadIdx.x;
    const int row0 = blockIdx.x * 64;

    for (int e = t; e < 512; e += 256)
        nbs[e >> 3][e & 7] = nbr[row0 * 8 + e];

    {   // stage self rows transposed
        const int r = t >> 2, cc = (t & 3) * 16;
        const float* p = x + (size_t)(row0 + r) * 64 + cc;
        const float4 v0 = *(const float4*)(p + 0);
        const float4 v1 = *(const float4*)(p + 4);
        const float4 v2 = *(const float4*)(p + 8);
        const float4 v3 = *(const float4*)(p + 12);
        xT[cc + 0][r] = v0.x; xT[cc + 1][r] = v0.y; xT[cc + 2][r] = v0.z; xT[cc + 3][r] = v0.w;
        xT[cc + 4][r] = v1.x; xT[cc + 5][r] = v1.y; xT[cc + 6][r] = v1.z; xT[cc + 7][r] = v1.w;
        xT[cc + 8][r] = v2.x; xT[cc + 9][r] = v2.y; xT[cc + 10][r] = v2.z; xT[cc + 11][r] = v2.w;
        xT[cc + 12][r] = v3.x; xT[cc + 13][r] = v3.y; xT[cc + 14][r] = v3.z; xT[cc + 15][r] = v3.w;
    }
    __syncthreads();

    {   // neighbor-mean gather: 32 independent b128 loads/thread
        const int r = t >> 2, cc = (t & 3) * 16;
        float4 a0 = {0,0,0,0}, a1 = {0,0,0,0}, a2 = {0,0,0,0}, a3 = {0,0,0,0};
        #pragma unroll
        for (int j = 0; j < 8; ++j) {
            const float* p = x + (size_t)nbs[r][j] * 64 + cc;
            const float4 v0 = *(const float4*)(p + 0);
            const float4 v1 = *(const float4*)(p + 4);
            const float4 v2 = *(const float4*)(p + 8);
            const float4 v3 = *(const float4*)(p + 12);
            a0.x += v0.x; a0.y += v0.y; a0.z += v0.z; a0.w += v0.w;
            a1.x += v1.x; a1.y += v1.y; a1.z += v1.z; a1.w += v1.w;
            a2.x += v2.x; a2.y += v2.y; a2.z += v2.z; a2.w += v2.w;
            a3.x += v3.x; a3.y += v3.y; a3.z += v3.z; a3.w += v3.w;
        }
        mT[cc + 0][r] = a0.x * 0.125f; mT[cc + 1][r] = a0.y * 0.125f;
        mT[cc + 2][r] = a0.z * 0.125f; mT[cc + 3][r] = a0.w * 0.125f;
        mT[cc + 4][r] = a1.x * 0.125f; mT[cc + 5][r] = a1.y * 0.125f;
        mT[cc + 6][r] = a1.z * 0.125f; mT[cc + 7][r] = a1.w * 0.125f;
        mT[cc + 8][r] = a2.x * 0.125f; mT[cc + 9][r] = a2.y * 0.125f;
        mT[cc + 10][r] = a2.z * 0.125f; mT[cc + 11][r] = a2.w * 0.125f;
        mT[cc + 12][r] = a3.x * 0.125f; mT[cc + 13][r] = a3.y * 0.125f;
        mT[cc + 14][r] = a3.z * 0.125f; mT[cc + 15][r] = a3.w * 0.125f;
    }
    __syncthreads();

    const int cg = t & 15, rg = t >> 4;
    const int c0 = cg * 4, r0 = rg * 4;

    // agg = nm @ vW + vb
    float ag[4][4] = {{0.f}};
    #pragma unroll 4
    for (int q = 0; q < 64; ++q) {
        const float4 wv = *(const float4*)&vW[q * 64 + c0];
        const float4 av = *(const float4*)&mT[q][r0];
        ag[0][0] += av.x * wv.x; ag[0][1] += av.x * wv.y; ag[0][2] += av.x * wv.z; ag[0][3] += av.x * wv.w;
        ag[1][0] += av.y * wv.x; ag[1][1] += av.y * wv.y; ag[1][2] += av.y * wv.z; ag[1][3] += av.y * wv.w;
        ag[2][0] += av.z * wv.x; ag[2][1] += av.z * wv.y; ag[2][2] += av.z * wv.z; ag[2][3] += av.z * wv.w;
        ag[3][0] += av.w * wv.x; ag[3][1] += av.w * wv.y; ag[3][2] += av.w * wv.z; ag[3][3] += av.w * wv.w;
    }
    {
        const float4 vbv = *(const float4*)&vb[c0];
        #pragma unroll
        for (int i = 0; i < 4; ++i) {
            ag[i][0] += vbv.x; ag[i][1] += vbv.y; ag[i][2] += vbv.z; ag[i][3] += vbv.w;
        }
    }
    __syncthreads();
    // write agg transposed back into mT
    #pragma unroll
    for (int i = 0; i < 4; ++i) {
        mT[c0 + 0][r0 + i] = ag[i][0];
        mT[c0 + 1][r0 + i] = ag[i][1];
        mT[c0 + 2][r0 + i] = ag[i][2];
        mT[c0 + 3][r0 + i] = ag[i][3];
    }
    __syncthreads();

    // x_next = [x | agg] @ wW + wb
    float acc[4][4];
    {
        const float4 wbv = *(const float4*)&wb[c0];
        #pragma unroll
        for (int i = 0; i < 4; ++i) {
            acc[i][0] = wbv.x; acc[i][1] = wbv.y; acc[i][2] = wbv.z; acc[i][3] = wbv.w;
        }
    }
    #pragma unroll 4
    for (int q = 0; q < 64; ++q) {
        const float4 wv = *(const float4*)&wW[q * 64 + c0];
        const float4 av = *(const float4*)&xT[q][r0];
        acc[0][0] += av.x * wv.x; acc[0][1] += av.x * wv.y; acc[0][2] += av.x * wv.z; acc[0][3] += av.x * wv.w;
        acc[1][0] += av.y * wv.x; acc[1][1] += av.y * wv.y; acc[1][2] += av.y * wv.z; acc[1][3] += av.y * wv.w;
        acc[2][0] += av.z * wv.x; acc[2][1] += av.z * wv.y; acc[2][2] += av.z * wv.z; acc[2][3] += av.z * wv.w;
        acc[3][0] += av.w * wv.x; acc[3][1] += av.w * wv.y; acc[3][2] += av.w * wv.z; acc[3][3] += av.w * wv.w;
    }
    #pragma unroll 4
    for (int q = 0; q < 64; ++q) {
        const float4 wv = *(const float4*)&wW[(64 + q) * 64 + c0];
        const float4 av = *(const float4*)&mT[q][r0];
        acc[0][0] += av.x * wv.x; acc[0][1] += av.x * wv.y; acc[0][2] += av.x * wv.z; acc[0][3] += av.x * wv.w;
        acc[1][0] += av.y * wv.x; acc[1][1] += av.y * wv.y; acc[1][2] += av.y * wv.z; acc[1][3] += av.y * wv.w;
        acc[2][0] += av.z * wv.x; acc[2][1] += av.z * wv.y; acc[2][2] += av.z * wv.z; acc[2][3] += av.z * wv.w;
        acc[3][0] += av.w * wv.x; acc[3][1] += av.w * wv.y; acc[3][2] += av.w * wv.z; acc[3][3] += av.w * wv.w;
    }

    if (!finalize) {
        #pragma unroll
        for (int i = 0; i < 4; ++i) {
            float4 o;
            o.x = fmaxf(acc[i][0], 0.f); o.y = fmaxf(acc[i][1], 0.f);
            o.z = fmaxf(acc[i][2], 0.f); o.w = fmaxf(acc[i][3], 0.f);
            *(float4*)&out[(size_t)(row0 + r0 + i) * 64 + c0] = o;
        }
    } else {
        // fused row L2-normalize: reduce across the 16 col-group lanes
        float ss[4];
        #pragma unroll
        for (int i = 0; i < 4; ++i)
            ss[i] = acc[i][0] * acc[i][0] + acc[i][1] * acc[i][1]
                  + acc[i][2] * acc[i][2] + acc[i][3] * acc[i][3];
        #pragma unroll
        for (int m = 1; m < 16; m <<= 1) {
            #pragma unroll
            for (int i = 0; i < 4; ++i)
                ss[i] += __shfl_xor(ss[i], m, 64);
        }
        #pragma unroll
        for (int i = 0; i < 4; ++i) {
            const float inv = 1.0f / fmaxf(sqrtf(ss[i]), 1e-12f);
            float4 o;
            o.x = acc[i][0] * inv; o.y = acc[i][1] * inv;
            o.z = acc[i][2] * inv; o.w = acc[i][3] * inv;
            *(float4*)&out[(size_t)(row0 + r0 + i) * 64 + c0] = o;
        }
    }
}

extern "C" void kernel_launch(void* const* d_in, const int* in_sizes, int n_in,
                              void* d_out, int out_size, void* d_ws, size_t ws_size,
                              hipStream_t stream) {
    const float* user_id_emb        = (const float*)d_in[0];
    const float* item_id_emb        = (const float*)d_in[1];
    const float* user_feat_table    = (const float*)d_in[2];
    const float* item_feat_table    = (const float*)d_in[3];
    const float* word_emb           = (const float*)d_in[4];
    const float* user_numeric       = (const float*)d_in[5];
    const float* item_numeric       = (const float*)d_in[6];
    const float* user_word_embedding= (const float*)d_in[7];
    const float* item_word_embedding= (const float*)d_in[8];
    const float* item_sentence_emb  = (const float*)d_in[9];
    const float* user_num_W         = (const float*)d_in[10];
    const float* user_num_b         = (const float*)d_in[11];
    const float* item_num_W         = (const float*)d_in[12];
    const float* item_num_b         = (const float*)d_in[13];
    const float* user_proj_W        = (const float*)d_in[14];
    const float* user_proj_b        = (const float*)d_in[15];
    const float* item_proj_W        = (const float*)d_in[16];
    const float* item_proj_b        = (const float*)d_in[17];
    const float* w_W                = (const float*)d_in[18];
    const float* w_b                = (const float*)d_in[19];
    const float* v_W                = (const float*)d_in[20];
    const float* v_b                = (const float*)d_in[21];
    const int*   user_feat_idx      = (const int*)d_in[22];
    const int*   item_feat_idx      = (const int*)d_in[23];
    const int*   user_text_idx      = (const int*)d_in[24];
    const int*   item_text_idx      = (const int*)d_in[25];
    const int*   neighbors          = (const int*)d_in[26];

    float* x0 = (float*)d_ws;       // 51.2 MB scratch
    float* x1 = (float*)d_out;

    node_init_kernel<<<(NU + 63) / 64, 256, 0, stream>>>(
        user_id_emb, user_feat_table, word_emb, user_numeric,
        user_word_embedding, nullptr, user_feat_idx, user_text_idx,
        user_proj_W, user_proj_b, user_num_W, user_num_b, x0, NU, KU, 0);
    node_init_kernel<<<(NI + 63) / 64, 256, 0, stream>>>(
        item_id_emb, item_feat_table, word_emb, item_numeric,
        item_word_embedding, item_sentence_emb, item_feat_idx, item_text_idx,
        item_proj_W, item_proj_b, item_num_W, item_num_b, x0, NI, KI, NU);

    // layer 0: x0 -> x1 (relu)
    gnn_layer_kernel<<<NTOT / 64, 256, 0, stream>>>(
        x0, neighbors, v_W, v_b, w_W, w_b, x1, 0);
    // layer 1 + fused normalize: x1 -> x0
    gnn_layer_kernel<<<NTOT / 64, 256, 0, stream>>>(
        x1, neighbors, v_W + 64 * 64, v_b + 64, w_W + 128 * 64, w_b + 64, x0, 1);

    hipMemcpyAsync(d_out, x0, (size_t)SZ * sizeof(float),
                   hipMemcpyDeviceToDevice, stream);
}

// Round 3
// 895.338 us; speedup vs baseline: 2.0341x; 1.9525x over previous
//
#include <hip/hip_runtime.h>

#define NU 150000
#define NI 50000
#define NTOT 200000
#define KU 524
#define KI 1292
#define SZ (NTOT * 64)

__device__ __forceinline__ float4 ld4(const float* p) { return *(const float4*)p; }

// ---------------------------------------------------------------------------
// Fused node-feature build + projection. 64 rows/block, k-tiles of 64.
// Row-major LDS tile a[64][68]. Staging: each thread owns (row r, 16-col chunk),
// issues all global loads for the chunk batched, then 4 b128 LDS writes.
// GEMM: 4x4 register tile per thread, A-reads are 16-lane broadcast b128.
// ---------------------------------------------------------------------------
__global__ __launch_bounds__(256, 4) void node_init_kernel(
    const float* __restrict__ id_emb, const float* __restrict__ feat_table,
    const float* __restrict__ word_emb, const float* __restrict__ numeric,
    const float* __restrict__ wordvec, const float* __restrict__ sentence,
    const int* __restrict__ feat_idx, const int* __restrict__ text_idx,
    const float* __restrict__ projW, const float* __restrict__ projb,
    const float* __restrict__ numW, const float* __restrict__ numb,
    float* __restrict__ x_out, int n, int Ktot, int row_off)
{
    __shared__ __align__(16) float a[64][68];
    __shared__ int   fi[64][5];
    __shared__ int   ti[64][24];
    __shared__ float nmr[64][10];
    const int t = threadIdx.x;
    const int row0 = blockIdx.x * 64;

    for (int e = t; e < 64 * 5; e += 256) {
        const int r = e / 5, j = e - r * 5, row = row0 + r;
        fi[r][j] = (row < n) ? feat_idx[row * 5 + j] : 0;
    }
    for (int e = t; e < 64 * 24; e += 256) {
        const int r = e / 24, j = e - r * 24, row = row0 + r;
        ti[r][j] = (row < n) ? text_idx[row * 24 + j] : 0;
    }
    for (int e = t; e < 64 * 10; e += 256) {
        const int r = e / 10, j = e - r * 10, row = row0 + r;
        nmr[r][j] = (row < n) ? numeric[(size_t)row * 10 + j] : 0.f;
    }
    __syncthreads();

    const int r  = t >> 2;            // staging row 0..63
    const int cq = (t & 3) * 16;      // staging chunk base within tile
    const int row = row0 + r;
    const bool valid = row < n;
    const int cg = t & 15, rg = t >> 4;
    const int c0 = cg * 4, r0 = rg * 4;
    float acc[4][4] = {{0.f}};

    for (int k0 = 0; k0 < Ktot; k0 += 64) {
        // ---- build chunk in registers (loads batched, overlap prev GEMM of
        //      other waves across the barrier) ----
        float4 vals[4];
        #pragma unroll
        for (int j = 0; j < 4; ++j) {
            const int k4 = k0 + cq + j * 4;
            float4 v = {0.f, 0.f, 0.f, 0.f};
            if (valid && k4 < Ktot) {
                if (k4 >= 524) {
                    v = ld4(sentence + (size_t)row * 768 + (k4 - 524));
                } else if (k4 >= 224) {
                    v = ld4(wordvec + (size_t)row * 300 + (k4 - 224));
                } else if (k4 >= 128) {
                    const int f = (k4 - 128) >> 5, c = (k4 - 128) & 31;
                    float4 s = {0.f, 0.f, 0.f, 0.f};
                    #pragma unroll
                    for (int m = 0; m < 8; ++m) {
                        const float4 g = ld4(word_emb + (size_t)ti[r][f * 8 + m] * 32 + c);
                        s.x += g.x; s.y += g.y; s.z += g.z; s.w += g.w;
                    }
                    v.x = s.x * 0.125f; v.y = s.y * 0.125f;
                    v.z = s.z * 0.125f; v.w = s.w * 0.125f;
                } else if (k4 >= 64) {
                    const int c = k4 - 64;
                    float4 s = {0.f, 0.f, 0.f, 0.f};
                    #pragma unroll
                    for (int m = 0; m < 5; ++m) {
                        const float4 g = ld4(feat_table + (size_t)fi[r][m] * 64 + c);
                        s.x += g.x; s.y += g.y; s.z += g.z; s.w += g.w;
                    }
                    v.x = s.x * 0.2f; v.y = s.y * 0.2f;
                    v.z = s.z * 0.2f; v.w = s.w * 0.2f;
                } else {
                    v = ld4(id_emb + (size_t)row * 64 + k4);
                }
            }
            vals[j] = v;
        }
        __syncthreads();        // prev tile's GEMM readers done
        #pragma unroll
        for (int j = 0; j < 4; ++j)
            *(float4*)&a[r][cq + j * 4] = vals[j];
        __syncthreads();        // tile visible

        // ---- register-tiled GEMM ----
        const int klim = min(64, Ktot - k0);
        for (int q = 0; q < klim; q += 4) {
            const float4 w0 = ld4(projW + (size_t)(k0 + q + 0) * 64 + c0);
            const float4 w1 = ld4(projW + (size_t)(k0 + q + 1) * 64 + c0);
            const float4 w2 = ld4(projW + (size_t)(k0 + q + 2) * 64 + c0);
            const float4 w3 = ld4(projW + (size_t)(k0 + q + 3) * 64 + c0);
            #pragma unroll
            for (int i = 0; i < 4; ++i) {
                const float4 av = ld4(&a[r0 + i][q]);
                acc[i][0] += av.x * w0.x + av.y * w1.x + av.z * w2.x + av.w * w3.x;
                acc[i][1] += av.x * w0.y + av.y * w1.y + av.z * w2.y + av.w * w3.y;
                acc[i][2] += av.x * w0.z + av.y * w1.z + av.z * w2.z + av.w * w3.z;
                acc[i][3] += av.x * w0.w + av.y * w1.w + av.z * w2.w + av.w * w3.w;
            }
        }
    }

    // ---- epilogue: numeric side-GEMM + biases ----
    #pragma unroll
    for (int m = 0; m < 10; ++m) {
        const float4 wn = ld4(numW + m * 64 + c0);
        #pragma unroll
        for (int i = 0; i < 4; ++i) {
            const float nv = nmr[r0 + i][m];
            acc[i][0] += nv * wn.x; acc[i][1] += nv * wn.y;
            acc[i][2] += nv * wn.z; acc[i][3] += nv * wn.w;
        }
    }
    const float4 pbv = ld4(projb + c0);
    const float4 nbv = ld4(numb + c0);
    #pragma unroll
    for (int i = 0; i < 4; ++i) {
        const int orow = row0 + r0 + i;
        if (orow < n) {
            float4 o;
            o.x = acc[i][0] + pbv.x + nbv.x;
            o.y = acc[i][1] + pbv.y + nbv.y;
            o.z = acc[i][2] + pbv.z + nbv.z;
            o.w = acc[i][3] + pbv.w + nbv.w;
            *(float4*)&x_out[(size_t)(row_off + orow) * 64 + c0] = o;
        }
    }
}

// ---------------------------------------------------------------------------
// GNN layer. 64 rows/block, row-major LDS tiles, 4x4 register GEMMs.
// finalize=0: relu.  finalize=1: fused row L2-normalize.
// ---------------------------------------------------------------------------
__global__ __launch_bounds__(256, 4) void gnn_layer_kernel(
    const float* __restrict__ x, const int* __restrict__ nbr,
    const float* __restrict__ vW, const float* __restrict__ vb,
    const float* __restrict__ wW, const float* __restrict__ wb,
    float* __restrict__ out, int finalize)
{
    __shared__ __align__(16) float xs[64][68];
    __shared__ __align__(16) float nm[64][68];
    __shared__ int nbs[64][8];
    const int t = threadIdx.x;
    const int row0 = blockIdx.x * 64;

    for (int e = t; e < 512; e += 256)
        nbs[e >> 3][e & 7] = nbr[row0 * 8 + e];

    const int r  = t >> 2;
    const int cq = (t & 3) * 16;
    __syncthreads();

    {   // self rows + neighbor-mean, all loads batched
        const float* ps = x + (size_t)(row0 + r) * 64 + cq;
        float4 sv[4];
        #pragma unroll
        for (int j = 0; j < 4; ++j) sv[j] = ld4(ps + j * 4);

        float4 ac[4] = {{0,0,0,0},{0,0,0,0},{0,0,0,0},{0,0,0,0}};
        #pragma unroll
        for (int m = 0; m < 8; ++m) {
            const float* p = x + (size_t)nbs[r][m] * 64 + cq;
            #pragma unroll
            for (int j = 0; j < 4; ++j) {
                const float4 g = ld4(p + j * 4);
                ac[j].x += g.x; ac[j].y += g.y; ac[j].z += g.z; ac[j].w += g.w;
            }
        }
        #pragma unroll
        for (int j = 0; j < 4; ++j) {
            *(float4*)&xs[r][cq + j * 4] = sv[j];
            float4 o;
            o.x = ac[j].x * 0.125f; o.y = ac[j].y * 0.125f;
            o.z = ac[j].z * 0.125f; o.w = ac[j].w * 0.125f;
            *(float4*)&nm[r][cq + j * 4] = o;
        }
    }
    __syncthreads();

    const int cg = t & 15, rg = t >> 4;
    const int c0 = cg * 4, r0 = rg * 4;

    // agg = nm @ vW + vb
    float ag[4][4] = {{0.f}};
    for (int q = 0; q < 64; q += 4) {
        const float4 w0 = ld4(vW + (q + 0) * 64 + c0);
        const float4 w1 = ld4(vW + (q + 1) * 64 + c0);
        const float4 w2 = ld4(vW + (q + 2) * 64 + c0);
        const float4 w3 = ld4(vW + (q + 3) * 64 + c0);
        #pragma unroll
        for (int i = 0; i < 4; ++i) {
            const float4 av = ld4(&nm[r0 + i][q]);
            ag[i][0] += av.x * w0.x + av.y * w1.x + av.z * w2.x + av.w * w3.x;
            ag[i][1] += av.x * w0.y + av.y * w1.y + av.z * w2.y + av.w * w3.y;
            ag[i][2] += av.x * w0.z + av.y * w1.z + av.z * w2.z + av.w * w3.z;
            ag[i][3] += av.x * w0.w + av.y * w1.w + av.z * w2.w + av.w * w3.w;
        }
    }
    __syncthreads();            // nm readers done
    {
        const float4 vbv = ld4(vb + c0);
        #pragma unroll
        for (int i = 0; i < 4; ++i) {
            float4 o;
            o.x = ag[i][0] + vbv.x; o.y = ag[i][1] + vbv.y;
            o.z = ag[i][2] + vbv.z; o.w = ag[i][3] + vbv.w;
            *(float4*)&nm[r0 + i][c0] = o;
        }
    }
    __syncthreads();

    // x_next = [xs | agg] @ wW + wb
    float acc[4][4];
    {
        const float4 wbv = ld4(wb + c0);
        #pragma unroll
        for (int i = 0; i < 4; ++i) {
            acc[i][0] = wbv.x; acc[i][1] = wbv.y;
            acc[i][2] = wbv.z; acc[i][3] = wbv.w;
        }
    }
    for (int q = 0; q < 64; q += 4) {
        const float4 w0 = ld4(wW + (q + 0) * 64 + c0);
        const float4 w1 = ld4(wW + (q + 1) * 64 + c0);
        const float4 w2 = ld4(wW + (q + 2) * 64 + c0);
        const float4 w3 = ld4(wW + (q + 3) * 64 + c0);
        #pragma unroll
        for (int i = 0; i < 4; ++i) {
            const float4 av = ld4(&xs[r0 + i][q]);
            acc[i][0] += av.x * w0.x + av.y * w1.x + av.z * w2.x + av.w * w3.x;
            acc[i][1] += av.x * w0.y + av.y * w1.y + av.z * w2.y + av.w * w3.y;
            acc[i][2] += av.x * w0.z + av.y * w1.z + av.z * w2.z + av.w * w3.z;
            acc[i][3] += av.x * w0.w + av.y * w1.w + av.z * w2.w + av.w * w3.w;
        }
    }
    for (int q = 0; q < 64; q += 4) {
        const float4 w0 = ld4(wW + (64 + q + 0) * 64 + c0);
        const float4 w1 = ld4(wW + (64 + q + 1) * 64 + c0);
        const float4 w2 = ld4(wW + (64 + q + 2) * 64 + c0);
        const float4 w3 = ld4(wW + (64 + q + 3) * 64 + c0);
        #pragma unroll
        for (int i = 0; i < 4; ++i) {
            const float4 av = ld4(&nm[r0 + i][q]);
            acc[i][0] += av.x * w0.x + av.y * w1.x + av.z * w2.x + av.w * w3.x;
            acc[i][1] += av.x * w0.y + av.y * w1.y + av.z * w2.y + av.w * w3.y;
            acc[i][2] += av.x * w0.z + av.y * w1.z + av.z * w2.z + av.w * w3.z;
            acc[i][3] += av.x * w0.w + av.y * w1.w + av.z * w2.w + av.w * w3.w;
        }
    }

    if (!finalize) {
        #pragma unroll
        for (int i = 0; i < 4; ++i) {
            float4 o;
            o.x = fmaxf(acc[i][0], 0.f); o.y = fmaxf(acc[i][1], 0.f);
            o.z = fmaxf(acc[i][2], 0.f); o.w = fmaxf(acc[i][3], 0.f);
            *(float4*)&out[(size_t)(row0 + r0 + i) * 64 + c0] = o;
        }
    } else {
        float ss[4];
        #pragma unroll
        for (int i = 0; i < 4; ++i)
            ss[i] = acc[i][0] * acc[i][0] + acc[i][1] * acc[i][1]
                  + acc[i][2] * acc[i][2] + acc[i][3] * acc[i][3];
        #pragma unroll
        for (int m = 1; m < 16; m <<= 1) {
            #pragma unroll
            for (int i = 0; i < 4; ++i)
                ss[i] += __shfl_xor(ss[i], m, 64);
        }
        #pragma unroll
        for (int i = 0; i < 4; ++i) {
            const float inv = 1.0f / fmaxf(sqrtf(ss[i]), 1e-12f);
            float4 o;
            o.x = acc[i][0] * inv; o.y = acc[i][1] * inv;
            o.z = acc[i][2] * inv; o.w = acc[i][3] * inv;
            *(float4*)&out[(size_t)(row0 + r0 + i) * 64 + c0] = o;
        }
    }
}

extern "C" void kernel_launch(void* const* d_in, const int* in_sizes, int n_in,
                              void* d_out, int out_size, void* d_ws, size_t ws_size,
                              hipStream_t stream) {
    const float* user_id_emb        = (const float*)d_in[0];
    const float* item_id_emb        = (const float*)d_in[1];
    const float* user_feat_table    = (const float*)d_in[2];
    const float* item_feat_table    = (const float*)d_in[3];
    const float* word_emb           = (const float*)d_in[4];
    const float* user_numeric       = (const float*)d_in[5];
    const float* item_numeric       = (const float*)d_in[6];
    const float* user_word_embedding= (const float*)d_in[7];
    const float* item_word_embedding= (const float*)d_in[8];
    const float* item_sentence_emb  = (const float*)d_in[9];
    const float* user_num_W         = (const float*)d_in[10];
    const float* user_num_b         = (const float*)d_in[11];
    const float* item_num_W         = (const float*)d_in[12];
    const float* item_num_b         = (const float*)d_in[13];
    const float* user_proj_W        = (const float*)d_in[14];
    const float* user_proj_b        = (const float*)d_in[15];
    const float* item_proj_W        = (const float*)d_in[16];
    const float* item_proj_b        = (const float*)d_in[17];
    const float* w_W                = (const float*)d_in[18];
    const float* w_b                = (const float*)d_in[19];
    const float* v_W                = (const float*)d_in[20];
    const float* v_b                = (const float*)d_in[21];
    const int*   user_feat_idx      = (const int*)d_in[22];
    const int*   item_feat_idx      = (const int*)d_in[23];
    const int*   user_text_idx      = (const int*)d_in[24];
    const int*   item_text_idx      = (const int*)d_in[25];
    const int*   neighbors          = (const int*)d_in[26];

    float* x0 = (float*)d_ws;
    const bool two_buf = ws_size >= (size_t)2 * SZ * sizeof(float);
    float* x1 = two_buf ? x0 + SZ : (float*)d_out;

    node_init_kernel<<<(NU + 63) / 64, 256, 0, stream>>>(
        user_id_emb, user_feat_table, word_emb, user_numeric,
        user_word_embedding, nullptr, user_feat_idx, user_text_idx,
        user_proj_W, user_proj_b, user_num_W, user_num_b, x0, NU, KU, 0);
    node_init_kernel<<<(NI + 63) / 64, 256, 0, stream>>>(
        item_id_emb, item_feat_table, word_emb, item_numeric,
        item_word_embedding, item_sentence_emb, item_feat_idx, item_text_idx,
        item_proj_W, item_proj_b, item_num_W, item_num_b, x0, NI, KI, NU);

    // layer 0: x0 -> x1 (relu)
    gnn_layer_kernel<<<NTOT / 64, 256, 0, stream>>>(
        x0, neighbors, v_W, v_b, w_W, w_b, x1, 0);
    // layer 1 + fused normalize: x1 -> (d_out | x0)
    gnn_layer_kernel<<<NTOT / 64, 256, 0, stream>>>(
        x1, neighbors, v_W + 64 * 64, v_b + 64, w_W + 128 * 64, w_b + 64,
        two_buf ? (float*)d_out : x0, 1);

    if (!two_buf)
        hipMemcpyAsync(d_out, x0, (size_t)SZ * sizeof(float),
                       hipMemcpyDeviceToDevice, stream);
}

// Round 4
// 591.163 us; speedup vs baseline: 3.0807x; 1.5145x over previous
//
#include <hip/hip_runtime.h>

typedef __attribute__((ext_vector_type(8))) short bf16x8;
typedef __attribute__((ext_vector_type(4))) float f32x4;

#define NU 150000
#define NI 50000
#define NTOT 200000
#define KU 524
#define KUP 576
#define KI 1292
#define KIP 1344

__device__ __forceinline__ float4 ld4(const float* p) { return *(const float4*)p; }

__device__ __forceinline__ unsigned short bf16r(float x) {
    unsigned u = __float_as_uint(x);
    u += 0x7fff + ((u >> 16) & 1);
    return (unsigned short)(u >> 16);
}
__device__ __forceinline__ unsigned pk2(float lo, float hi) {
    unsigned a = __float_as_uint(lo), b = __float_as_uint(hi);
    a += 0x7fff + ((a >> 16) & 1);
    b += 0x7fff + ((b >> 16) & 1);
    return (a >> 16) | (b & 0xffff0000u);
}
__device__ __forceinline__ float bflo(unsigned s) { return __uint_as_float(s << 16); }
__device__ __forceinline__ float bfhi(unsigned s) { return __uint_as_float(s & 0xffff0000u); }

// W [K][64] fp32 -> WT [64][Kpad] bf16 (zero-padded K)
__global__ void prep_wt(const float* __restrict__ src, unsigned short* __restrict__ dst,
                        int K, int Kpad) {
    const int c = blockIdx.y;
    const int k = blockIdx.x * 256 + threadIdx.x;
    if (k >= Kpad) return;
    dst[(size_t)c * Kpad + k] = (k < K) ? bf16r(src[(size_t)k * 64 + c]) : (unsigned short)0;
}

// ---------------------------------------------------------------------------
// Fused node-feature build + projection via MFMA. 64 rows/block, 4 waves.
// k-tiles of 64: stage A bf16 [64][72] in LDS; wave w computes rows w*16..+15
// over 4 col-tiles of 16. Pipeline: store(k) -> load(k+1) -> mfma(k).
// ---------------------------------------------------------------------------
__global__ __launch_bounds__(256, 6) void node_init_kernel(
    const float* __restrict__ id_emb, const float* __restrict__ feat_table,
    const float* __restrict__ word_emb, const float* __restrict__ numeric,
    const float* __restrict__ wordvec, const float* __restrict__ sentence,
    const int* __restrict__ feat_idx, const int* __restrict__ text_idx,
    const unsigned short* __restrict__ WT, const float* __restrict__ projb,
    const float* __restrict__ numW, const float* __restrict__ numb,
    unsigned short* __restrict__ x_out, int n, int Ktot, int Kpad, int row_off)
{
    __shared__ __align__(16) unsigned short aS[64][72];
    __shared__ unsigned short fiS[64][5];
    __shared__ unsigned short tiS[64][24];
    __shared__ float nmrS[64][10];

    const int t = threadIdx.x;
    const int row0 = blockIdx.x * 64;

    for (int e = t; e < 64 * 5; e += 256) {
        const int r = e / 5, j = e - r * 5, row = row0 + r;
        fiS[r][j] = (row < n) ? (unsigned short)feat_idx[row * 5 + j] : (unsigned short)0;
    }
    for (int e = t; e < 64 * 24; e += 256) {
        const int r = e / 24, j = e - r * 24, row = row0 + r;
        tiS[r][j] = (row < n) ? (unsigned short)text_idx[row * 24 + j] : (unsigned short)0;
    }
    for (int e = t; e < 64 * 10; e += 256) {
        const int r = e / 10, j = e - r * 10, row = row0 + r;
        nmrS[r][j] = (row < n) ? numeric[(size_t)row * 10 + j] : 0.f;
    }
    __syncthreads();

    const int sr  = t >> 2;            // staging row
    const int scq = (t & 3) * 16;      // staging col chunk (floats)
    const int srow = row0 + sr;
    const bool svalid = srow < n;

    const int lane = t & 63;
    const int w16 = (t >> 6) * 16;
    const int l15 = lane & 15;
    const int hi8 = (lane >> 4) * 8;
    const int g4  = (lane >> 4) * 4;

    f32x4 acc[4];
    #pragma unroll
    for (int ct = 0; ct < 4; ++ct) acc[ct] = (f32x4){0.f, 0.f, 0.f, 0.f};

    float4 vals[4];
    auto load_tile = [&](int kt) {
        #pragma unroll
        for (int j = 0; j < 4; ++j) {
            const int k4 = kt * 64 + scq + j * 4;
            float4 v = {0.f, 0.f, 0.f, 0.f};
            if (svalid && k4 < Ktot) {
                if (k4 >= 524) {
                    v = ld4(sentence + (size_t)srow * 768 + (k4 - 524));
                } else if (k4 >= 224) {
                    v = ld4(wordvec + (size_t)srow * 300 + (k4 - 224));
                } else if (k4 >= 128) {
                    const int f = (k4 - 128) >> 5, c = (k4 - 128) & 31;
                    float4 s = {0.f, 0.f, 0.f, 0.f};
                    #pragma unroll
                    for (int m = 0; m < 8; ++m) {
                        const float4 g = ld4(word_emb + (size_t)tiS[sr][f * 8 + m] * 32 + c);
                        s.x += g.x; s.y += g.y; s.z += g.z; s.w += g.w;
                    }
                    v.x = s.x * 0.125f; v.y = s.y * 0.125f;
                    v.z = s.z * 0.125f; v.w = s.w * 0.125f;
                } else if (k4 >= 64) {
                    const int c = k4 - 64;
                    float4 s = {0.f, 0.f, 0.f, 0.f};
                    #pragma unroll
                    for (int m = 0; m < 5; ++m) {
                        const float4 g = ld4(feat_table + (size_t)fiS[sr][m] * 64 + c);
                        s.x += g.x; s.y += g.y; s.z += g.z; s.w += g.w;
                    }
                    v.x = s.x * 0.2f; v.y = s.y * 0.2f;
                    v.z = s.z * 0.2f; v.w = s.w * 0.2f;
                } else {
                    v = ld4(id_emb + (size_t)srow * 64 + k4);
                }
            }
            vals[j] = v;
        }
    };

    const int NT = Kpad / 64;
    load_tile(0);
    for (int kt = 0; kt < NT; ++kt) {
        __syncthreads();   // previous tile's MFMA readers done
        #pragma unroll
        for (int j = 0; j < 2; ++j) {
            const float4 a0 = vals[2 * j], a1 = vals[2 * j + 1];
            uint4 pk;
            pk.x = pk2(a0.x, a0.y); pk.y = pk2(a0.z, a0.w);
            pk.z = pk2(a1.x, a1.y); pk.w = pk2(a1.z, a1.w);
            *(uint4*)&aS[sr][scq + j * 8] = pk;
        }
        __syncthreads();   // tile visible
        if (kt + 1 < NT) load_tile(kt + 1);   // prefetch (hidden under MFMA+barriers)
        #pragma unroll
        for (int ks = 0; ks < 2; ++ks) {
            const bf16x8 af = *(const bf16x8*)&aS[w16 + l15][ks * 32 + hi8];
            #pragma unroll
            for (int ct = 0; ct < 4; ++ct) {
                const bf16x8 bfr = *(const bf16x8*)&WT[(size_t)(ct * 16 + l15) * Kpad
                                                      + kt * 64 + ks * 32 + hi8];
                acc[ct] = __builtin_amdgcn_mfma_f32_16x16x32_bf16(af, bfr, acc[ct], 0, 0, 0);
            }
        }
    }

    // epilogue: proj bias + numeric side-GEMM + num bias, write bf16
    #pragma unroll
    for (int ct = 0; ct < 4; ++ct) {
        const int c = ct * 16 + l15;
        const float pb = projb[c] + numb[c];
        float wn[10];
        #pragma unroll
        for (int m = 0; m < 10; ++m) wn[m] = numW[m * 64 + c];
        #pragma unroll
        for (int j = 0; j < 4; ++j) {
            const int r = w16 + g4 + j;
            const int row = row0 + r;
            if (row < n) {
                float s = acc[ct][j] + pb;
                #pragma unroll
                for (int m = 0; m < 10; ++m) s += nmrS[r][m] * wn[m];
                x_out[(size_t)(row_off + row) * 64 + c] = bf16r(s);
            }
        }
    }
}

// ---------------------------------------------------------------------------
// GNN layer via MFMA. 64 rows/block. nm(bf16 LDS) -> agg MFMA -> ag(LDS) ->
// out = [x | ag] @ W2 (x A-frags read directly from global bf16).
// ---------------------------------------------------------------------------
__global__ __launch_bounds__(256, 6) void gnn_layer_kernel(
    const unsigned short* __restrict__ x, const int* __restrict__ nbr,
    const unsigned short* __restrict__ VT, const unsigned short* __restrict__ W2T,
    const float* __restrict__ vb, const float* __restrict__ wb,
    void* __restrict__ outp, int finalize)
{
    __shared__ __align__(16) unsigned short mS[64][72];
    __shared__ int nbs[64][8];
    const int t = threadIdx.x;
    const int row0 = blockIdx.x * 64;

    for (int e = t; e < 512; e += 256) nbs[e >> 3][e & 7] = nbr[row0 * 8 + e];
    __syncthreads();

    {   // neighbor mean -> mS (bf16)
        const int r = t >> 2, c16 = (t & 3) * 16;
        float s[16];
        #pragma unroll
        for (int i = 0; i < 16; ++i) s[i] = 0.f;
        #pragma unroll
        for (int m = 0; m < 8; ++m) {
            const unsigned short* p = x + (size_t)nbs[r][m] * 64 + c16;
            const uint4 q0 = *(const uint4*)p;
            const uint4 q1 = *(const uint4*)(p + 8);
            s[0] += bflo(q0.x); s[1] += bfhi(q0.x); s[2] += bflo(q0.y); s[3] += bfhi(q0.y);
            s[4] += bflo(q0.z); s[5] += bfhi(q0.z); s[6] += bflo(q0.w); s[7] += bfhi(q0.w);
            s[8] += bflo(q1.x); s[9] += bfhi(q1.x); s[10] += bflo(q1.y); s[11] += bfhi(q1.y);
            s[12] += bflo(q1.z); s[13] += bfhi(q1.z); s[14] += bflo(q1.w); s[15] += bfhi(q1.w);
        }
        uint4 o0, o1;
        o0.x = pk2(s[0] * 0.125f, s[1] * 0.125f);
        o0.y = pk2(s[2] * 0.125f, s[3] * 0.125f);
        o0.z = pk2(s[4] * 0.125f, s[5] * 0.125f);
        o0.w = pk2(s[6] * 0.125f, s[7] * 0.125f);
        o1.x = pk2(s[8] * 0.125f, s[9] * 0.125f);
        o1.y = pk2(s[10] * 0.125f, s[11] * 0.125f);
        o1.z = pk2(s[12] * 0.125f, s[13] * 0.125f);
        o1.w = pk2(s[14] * 0.125f, s[15] * 0.125f);
        *(uint4*)&mS[r][c16] = o0;
        *(uint4*)&mS[r][c16 + 8] = o1;
    }
    __syncthreads();

    const int lane = t & 63;
    const int w16 = (t >> 6) * 16;
    const int l15 = lane & 15;
    const int hi8 = (lane >> 4) * 8;
    const int g4  = (lane >> 4) * 4;

    // agg = nm @ vW
    f32x4 ag[4];
    #pragma unroll
    for (int ct = 0; ct < 4; ++ct) ag[ct] = (f32x4){0.f, 0.f, 0.f, 0.f};
    #pragma unroll
    for (int ks = 0; ks < 2; ++ks) {
        const bf16x8 af = *(const bf16x8*)&mS[w16 + l15][ks * 32 + hi8];
        #pragma unroll
        for (int ct = 0; ct < 4; ++ct) {
            const bf16x8 bfr = *(const bf16x8*)&VT[(ct * 16 + l15) * 64 + ks * 32 + hi8];
            ag[ct] = __builtin_amdgcn_mfma_f32_16x16x32_bf16(af, bfr, ag[ct], 0, 0, 0);
        }
    }
    __syncthreads();   // nm readers done
    #pragma unroll
    for (int ct = 0; ct < 4; ++ct) {
        const int c = ct * 16 + l15;
        const float b = vb[c];
        #pragma unroll
        for (int j = 0; j < 4; ++j)
            mS[w16 + g4 + j][c] = bf16r(ag[ct][j] + b);
    }
    __syncthreads();

    // out = [x | ag] @ wW
    f32x4 acc[4];
    #pragma unroll
    for (int ct = 0; ct < 4; ++ct) acc[ct] = (f32x4){0.f, 0.f, 0.f, 0.f};
    #pragma unroll
    for (int ks = 0; ks < 4; ++ks) {
        bf16x8 af;
        if (ks < 2) af = *(const bf16x8*)&x[(size_t)(row0 + w16 + l15) * 64 + ks * 32 + hi8];
        else        af = *(const bf16x8*)&mS[w16 + l15][(ks - 2) * 32 + hi8];
        #pragma unroll
        for (int ct = 0; ct < 4; ++ct) {
            const bf16x8 bfr = *(const bf16x8*)&W2T[(ct * 16 + l15) * 128 + ks * 32 + hi8];
            acc[ct] = __builtin_amdgcn_mfma_f32_16x16x32_bf16(af, bfr, acc[ct], 0, 0, 0);
        }
    }

    if (!finalize) {
        unsigned short* xo = (unsigned short*)outp;
        #pragma unroll
        for (int ct = 0; ct < 4; ++ct) {
            const int c = ct * 16 + l15;
            const float b = wb[c];
            #pragma unroll
            for (int j = 0; j < 4; ++j)
                xo[(size_t)(row0 + w16 + g4 + j) * 64 + c] = bf16r(fmaxf(acc[ct][j] + b, 0.f));
        }
    } else {
        float* fo = (float*)outp;
        float vc[4][4], ss[4];
        #pragma unroll
        for (int j = 0; j < 4; ++j) ss[j] = 0.f;
        #pragma unroll
        for (int ct = 0; ct < 4; ++ct) {
            const float b = wb[ct * 16 + l15];
            #pragma unroll
            for (int j = 0; j < 4; ++j) {
                vc[ct][j] = acc[ct][j] + b;
                ss[j] += vc[ct][j] * vc[ct][j];
            }
        }
        #pragma unroll
        for (int m = 1; m < 16; m <<= 1) {
            #pragma unroll
            for (int j = 0; j < 4; ++j) ss[j] += __shfl_xor(ss[j], m, 64);
        }
        #pragma unroll
        for (int j = 0; j < 4; ++j) ss[j] = 1.f / fmaxf(sqrtf(ss[j]), 1e-12f);
        #pragma unroll
        for (int ct = 0; ct < 4; ++ct) {
            const int c = ct * 16 + l15;
            #pragma unroll
            for (int j = 0; j < 4; ++j)
                fo[(size_t)(row0 + w16 + g4 + j) * 64 + c] = vc[ct][j] * ss[j];
        }
    }
}

extern "C" void kernel_launch(void* const* d_in, const int* in_sizes, int n_in,
                              void* d_out, int out_size, void* d_ws, size_t ws_size,
                              hipStream_t stream) {
    const float* user_id_emb        = (const float*)d_in[0];
    const float* item_id_emb        = (const float*)d_in[1];
    const float* user_feat_table    = (const float*)d_in[2];
    const float* item_feat_table    = (const float*)d_in[3];
    const float* word_emb           = (const float*)d_in[4];
    const float* user_numeric       = (const float*)d_in[5];
    const float* item_numeric       = (const float*)d_in[6];
    const float* user_word_embedding= (const float*)d_in[7];
    const float* item_word_embedding= (const float*)d_in[8];
    const float* item_sentence_emb  = (const float*)d_in[9];
    const float* user_num_W         = (const float*)d_in[10];
    const float* user_num_b         = (const float*)d_in[11];
    const float* item_num_W         = (const float*)d_in[12];
    const float* item_num_b         = (const float*)d_in[13];
    const float* user_proj_W        = (const float*)d_in[14];
    const float* user_proj_b        = (const float*)d_in[15];
    const float* item_proj_W        = (const float*)d_in[16];
    const float* item_proj_b        = (const float*)d_in[17];
    const float* w_W                = (const float*)d_in[18];
    const float* w_b                = (const float*)d_in[19];
    const float* v_W                = (const float*)d_in[20];
    const float* v_b                = (const float*)d_in[21];
    const int*   user_feat_idx      = (const int*)d_in[22];
    const int*   item_feat_idx      = (const int*)d_in[23];
    const int*   user_text_idx      = (const int*)d_in[24];
    const int*   item_text_idx      = (const int*)d_in[25];
    const int*   neighbors          = (const int*)d_in[26];

    // ws layout (bf16): x0 [NTOT][64], x1 [NTOT][64]  (fits exactly in SZ*4 bytes)
    unsigned short* x0 = (unsigned short*)d_ws;
    unsigned short* x1 = x0 + (size_t)NTOT * 64;

    // W prep area #1: tail of d_out (init/L1 never write d_out -> safe)
    const size_t prep_bytes = 2ull * 64 * (KUP + KIP + 64 + 128);   // 270336
    char* WTbase = (char*)d_out + (size_t)out_size * 4 - prep_bytes;
    unsigned short* WTu = (unsigned short*)WTbase;
    unsigned short* WTi = WTu + 64 * KUP;
    unsigned short* VT0 = WTi + 64 * KIP;
    unsigned short* W20 = VT0 + 64 * 64;
    // W prep area #2 (for layer 2, since L2 writes d_out): dead x0 region
    unsigned short* VT1 = (unsigned short*)d_ws;
    unsigned short* W21 = VT1 + 64 * 64;

    prep_wt<<<dim3((KUP + 255) / 256, 64), 256, 0, stream>>>(user_proj_W, WTu, KU, KUP);
    prep_wt<<<dim3((KIP + 255) / 256, 64), 256, 0, stream>>>(item_proj_W, WTi, KI, KIP);
    prep_wt<<<dim3(1, 64), 256, 0, stream>>>(v_W, VT0, 64, 64);
    prep_wt<<<dim3(1, 64), 256, 0, stream>>>(w_W, W20, 128, 128);

    node_init_kernel<<<(NU + 63) / 64, 256, 0, stream>>>(
        user_id_emb, user_feat_table, word_emb, user_numeric,
        user_word_embedding, nullptr, user_feat_idx, user_text_idx,
        WTu, user_proj_b, user_num_W, user_num_b, x0, NU, KU, KUP, 0);
    node_init_kernel<<<(NI + 63) / 64, 256, 0, stream>>>(
        item_id_emb, item_feat_table, word_emb, item_numeric,
        item_word_embedding, item_sentence_emb, item_feat_idx, item_text_idx,
        WTi, item_proj_b, item_num_W, item_num_b, x0, NI, KI, KIP, NU);

    // layer 0: x0 -> x1 (relu, bf16)
    gnn_layer_kernel<<<NTOT / 64, 256, 0, stream>>>(
        x0, neighbors, VT0, W20, v_b, w_b, x1, 0);

    // re-prep layer-1 weights into dead x0 region
    prep_wt<<<dim3(1, 64), 256, 0, stream>>>(v_W + 64 * 64, VT1, 64, 64);
    prep_wt<<<dim3(1, 64), 256, 0, stream>>>(w_W + 128 * 64, W21, 128, 128);

    // layer 1 + fused normalize: x1 -> d_out (fp32)
    gnn_layer_kernel<<<NTOT / 64, 256, 0, stream>>>(
        x1, neighbors, VT1, W21, v_b + 64, w_b + 64, d_out, 1);
}